// Round 1
// baseline (29.639 us; speedup 1.0000x reference)
//
#include <hip/hip_runtime.h>

// out[b,d] = sum_c w[b,c] * f[idx[b,c,0],d] * f[idx[b,c,1],d]   (w==0 -> padding, tail-contiguous)
// fallback: out[b,:] = f[target_nodes[b],:] when has_edge[b] <= 0
//
// Layout decisions:
//  - one 64-lane wave per output row b; each lane holds float2 (D=128 floats)
//  - 256-thread block = 4 waves = 4 rows; no syncthreads needed
//  - gathered feature-row loads are fully coalesced (64 lanes x 8B = 512B/row)

__global__ __launch_bounds__(256) void tmp_aggregate_kernel(
    const float*  __restrict__ features,      // [N, 128]
    const int*    __restrict__ target_nodes,  // [B]
    const int*    __restrict__ comb_idx,      // [B, cmax, 2]
    const float*  __restrict__ comb_w,        // [B, cmax]
    const float*  __restrict__ has_edge,      // [B]
    float*        __restrict__ out,           // [B, 128]
    int B, int cmax)
{
    const int lane = threadIdx.x & 63;
    // force wave-id uniform so comb_w/comb_idx loads can go scalar
    const int wave = __builtin_amdgcn_readfirstlane((int)(threadIdx.x >> 6));
    const int b = blockIdx.x * 4 + wave;
    if (b >= B) return;

    const float2* __restrict__ f2 = (const float2*)features;

    float2 acc = make_float2(0.f, 0.f);
    const long base = (long)b * cmax;

    for (int c = 0; c < cmax; ++c) {
        const float w = comb_w[base + c];
        if (w == 0.0f) break;                      // tail padding
        const int i0 = comb_idx[(base + c) * 2 + 0];
        const int i1 = comb_idx[(base + c) * 2 + 1];
        const float2 x = f2[(long)i0 * 64 + lane];
        const float2 y = f2[(long)i1 * 64 + lane];
        acc.x = fmaf(w * x.x, y.x, acc.x);
        acc.y = fmaf(w * x.y, y.y, acc.y);
    }

    if (!(has_edge[b] > 0.f)) {
        acc = f2[(long)target_nodes[b] * 64 + lane];
    }

    ((float2*)out)[(long)b * 64 + lane] = acc;
}

extern "C" void kernel_launch(void* const* d_in, const int* in_sizes, int n_in,
                              void* d_out, int out_size, void* d_ws, size_t ws_size,
                              hipStream_t stream) {
    const float* features     = (const float*)d_in[0];
    const int*   target_nodes = (const int*)d_in[1];
    const int*   comb_idx     = (const int*)d_in[2];
    const float* comb_w       = (const float*)d_in[3];
    const float* has_edge     = (const float*)d_in[4];
    float*       out          = (float*)d_out;

    const int B    = in_sizes[1];                 // 16384
    const int cmax = in_sizes[2] / (B * 2);       // combos per row (padded)

    const int rows_per_block = 4;                 // 4 waves x 1 row
    const int grid = (B + rows_per_block - 1) / rows_per_block;

    tmp_aggregate_kernel<<<grid, 256, 0, stream>>>(
        features, target_nodes, comb_idx, comb_w, has_edge, out, B, cmax);
}

// Round 2
// 22.677 us; speedup vs baseline: 1.3070x; 1.3070x over previous
//
#include <hip/hip_runtime.h>

// out[b,d] = sum_c w[b,c] * f[idx[b,c,0],d] * f[idx[b,c,1],d]   (w==0 -> padding, tail-contiguous)
// fallback: out[b,:] = f[target_nodes[b],:] when has_edge[b] <= 0
//
// Layout:
//  - one 64-lane wave per output row b; each lane holds float2 (D=128 floats)
//  - 256-thread block = 4 waves = 4 rows; no syncthreads
//  - per-row combo count computed once via wave ballot (padding is tail-contiguous),
//    then a branch-free counted loop -> compiler can pipeline gathers (MLP)

__global__ __launch_bounds__(256) void tmp_aggregate_kernel(
    const float*  __restrict__ features,      // [N, 128]
    const int*    __restrict__ target_nodes,  // [B]
    const int*    __restrict__ comb_idx,      // [B, cmax, 2]
    const float*  __restrict__ comb_w,        // [B, cmax]
    const float*  __restrict__ has_edge,      // [B]
    float*        __restrict__ out,           // [B, 128]
    int B, int cmax)
{
    const int lane = threadIdx.x & 63;
    const int wave = __builtin_amdgcn_readfirstlane((int)(threadIdx.x >> 6));
    const int b = blockIdx.x * 4 + wave;
    if (b >= B) return;

    const float2* __restrict__ f2 = (const float2*)features;
    const long base = (long)b * cmax;

    // --- count live combos for this row (w != 0), tail-contiguous padding ---
    int cnt = 0;
    for (int c0 = 0; c0 < cmax; c0 += 64) {
        const int c = c0 + lane;
        const float w = (c < cmax) ? comb_w[base + c] : 0.0f;
        const unsigned long long m = __ballot(w != 0.0f);
        cnt += __popcll(m);
        if (m != ~0ull) break;   // found the tail
    }

    // --- branch-free counted main loop (compiler can unroll + pipeline) ---
    float2 acc = make_float2(0.f, 0.f);
    const int2* __restrict__ idx2 = (const int2*)comb_idx;

    #pragma unroll 4
    for (int c = 0; c < cnt; ++c) {
        const float w  = comb_w[base + c];
        const int2  ix = idx2[base + c];
        const float2 x = f2[(long)ix.x * 64 + lane];
        const float2 y = f2[(long)ix.y * 64 + lane];
        acc.x = fmaf(w * x.x, y.x, acc.x);
        acc.y = fmaf(w * x.y, y.y, acc.y);
    }

    if (!(has_edge[b] > 0.f)) {
        acc = f2[(long)target_nodes[b] * 64 + lane];
    }

    __builtin_nontemporal_store(acc.x, &out[(long)b * 128 + lane * 2 + 0]);
    __builtin_nontemporal_store(acc.y, &out[(long)b * 128 + lane * 2 + 1]);
}

extern "C" void kernel_launch(void* const* d_in, const int* in_sizes, int n_in,
                              void* d_out, int out_size, void* d_ws, size_t ws_size,
                              hipStream_t stream) {
    const float* features     = (const float*)d_in[0];
    const int*   target_nodes = (const int*)d_in[1];
    const int*   comb_idx     = (const int*)d_in[2];
    const float* comb_w       = (const float*)d_in[3];
    const float* has_edge     = (const float*)d_in[4];
    float*       out          = (float*)d_out;

    const int B    = in_sizes[1];                 // 16384
    const int cmax = in_sizes[2] / (B * 2);       // combos per row (padded)

    const int rows_per_block = 4;                 // 4 waves x 1 row
    const int grid = (B + rows_per_block - 1) / rows_per_block;

    tmp_aggregate_kernel<<<grid, 256, 0, stream>>>(
        features, target_nodes, comb_idx, comb_w, has_edge, out, B, cmax);
}